// Round 3
// baseline (449.823 us; speedup 1.0000x reference)
//
#include <hip/hip_runtime.h>
#include <hip/hip_bf16.h>

#define LN_EPS 1e-5f

typedef __attribute__((ext_vector_type(8))) short bf16x8;
typedef __attribute__((ext_vector_type(4))) float f32x4;

__device__ __forceinline__ unsigned short f2bf(float f){
  unsigned u = __builtin_bit_cast(unsigned, f);
  u = (u + 0x7fffu + ((u >> 16) & 1u)) >> 16;
  return (unsigned short)u;
}
__device__ __forceinline__ float bf2f(unsigned short h){
  unsigned u = ((unsigned)h) << 16;
  return __builtin_bit_cast(float, u);
}
__device__ __forceinline__ void gll16(const void* g, void* l){
  __builtin_amdgcn_global_load_lds(
      (const __attribute__((address_space(1))) unsigned int*)(g),
      (__attribute__((address_space(3))) unsigned int*)(l), 16, 0, 0);
}

// ---------------------------------------------------------------------------
// Kernel 0: fold LN gamma into Wq.
//   gWqT[n][d] = bf16(g[d]*Wq[d][n]);  c12[n] = {sum_d b[d]*Wq[d][n], sum_d bf(g*W)}
// grid(8), 256 threads: block owns 64 n's; thread (c=n-off, q=d-chunk of 128)
// ---------------------------------------------------------------------------
__global__ void k_prep(const float* __restrict__ Wq, const float* __restrict__ ln_g,
                       const float* __restrict__ ln_b,
                       unsigned short* __restrict__ gWqT, float2* __restrict__ c12)
{
  __shared__ float r1[64][4], r2[64][4];
  const int tid = threadIdx.x;
  const int n0 = blockIdx.x * 64;
  const int c = tid & 63, q = tid >> 6;
  float c1p = 0.f, c2p = 0.f;
  for(int i=0;i<128;i+=4){
    ushort4 pk;
    unsigned short* pp = (unsigned short*)&pk;
    #pragma unroll
    for(int j=0;j<4;j++){
      const int d = q*128 + i + j;
      const float wv = Wq[(size_t)d*512 + n0 + c];
      const float gw = ln_g[d] * wv;
      const unsigned short hb = f2bf(gw);
      pp[j] = hb;
      c2p += bf2f(hb);
      c1p += ln_b[d] * wv;
    }
    *(ushort4*)(gWqT + (size_t)(n0 + c)*512 + q*128 + i) = pk;
  }
  r1[c][q] = c1p; r2[c][q] = c2p;
  __syncthreads();
  if(q == 0){
    float a = 0.f, b2 = 0.f;
    #pragma unroll
    for(int j=0;j<4;j++){ a += r1[c][j]; b2 += r2[c][j]; }
    c12[n0 + c] = make_float2(a, b2);
  }
}

// ---------------------------------------------------------------------------
// Kernel 1: cond LN + K/V projection (unchanged)
// ---------------------------------------------------------------------------
__global__ void k_condkv(const float* __restrict__ cond, const int* __restrict__ idx,
                         const float* __restrict__ tg, const float* __restrict__ tb,
                         const float* __restrict__ Wk, const float* __restrict__ bk,
                         const float* __restrict__ Wv, const float* __restrict__ bv,
                         float* __restrict__ kbuf, float* __restrict__ vbuf)
{
  __shared__ float cn[16][768];
  const int bc = blockIdx.z, nc = blockIdx.y, dc = blockIdx.x;
  const int b = idx[bc];
  const int n0 = nc * 16;
  int nrows = 77 - n0; if(nrows > 16) nrows = 16;
  const int w = threadIdx.x >> 6, lane = threadIdx.x & 63;

  for(int r = w; r < nrows; r += 4){
    const float* src = cond + ((size_t)b * 77 + n0 + r) * 768;
    float vals[12]; float s1 = 0.f, s2 = 0.f;
    #pragma unroll
    for(int i=0;i<12;i++){ float x = src[lane + i*64]; vals[i]=x; s1+=x; s2+=x*x; }
    #pragma unroll
    for(int off=1; off<64; off<<=1){ s1 += __shfl_xor(s1, off); s2 += __shfl_xor(s2, off); }
    const float mu  = s1 * (1.f/768.f);
    const float var = s2 * (1.f/768.f) - mu*mu;
    const float rs  = rsqrtf(var + LN_EPS);
    #pragma unroll
    for(int i=0;i<12;i++){ const int c2 = lane + i*64; cn[r][c2] = (vals[i]-mu)*rs*tg[c2] + tb[c2]; }
  }
  __syncthreads();

  const int dq = threadIdx.x & 63;
  const int part = threadIdx.x >> 6;
  const float* W    = (dc < 2) ? Wk : Wv;
  const float* bias = (dc < 2) ? bk : bv;
  float* obuf       = (dc < 2) ? kbuf : vbuf;
  const int d0 = (dc & 1) * 256 + dq * 4;

  float acc[4][4] = {};
  for(int i=0;i<768;i++){
    const float4 wv = *(const float4*)(W + (size_t)i * 512 + d0);
    #pragma unroll
    for(int j=0;j<4;j++){
      const float c = cn[part*4 + j][i];
      acc[j][0] += c * wv.x; acc[j][1] += c * wv.y;
      acc[j][2] += c * wv.z; acc[j][3] += c * wv.w;
    }
  }
  #pragma unroll
  for(int j=0;j<4;j++){
    const int r = part*4 + j, n = n0 + r;
    if(r < nrows){
      float4 o;
      o.x = acc[j][0] + bias[d0+0];
      o.y = acc[j][1] + bias[d0+1];
      o.z = acc[j][2] + bias[d0+2];
      o.w = acc[j][3] + bias[d0+3];
      *(float4*)(obuf + ((size_t)bc * 77 + n) * 512 + d0) = o;
    }
  }
}

// ---------------------------------------------------------------------------
// Kernel 2: per (h, bc): softmax K over tokens; ctxP = context in MFMA-B-frag
// packed layout: element (k,v) at ((((k>>5)*4+(v>>4))*4+((k>>3)&3))*16+(v&15))*8+(k&7)
// ---------------------------------------------------------------------------
__global__ void k_ctx(const float* __restrict__ kbuf, const float* __restrict__ vbuf,
                      unsigned short* __restrict__ ctxP)
{
  __shared__ float kk[77][64];
  __shared__ float vv[77][64];
  __shared__ float inv_s[64];
  const int h = blockIdx.x, bc = blockIdx.y;
  const int tid = threadIdx.x;
  for(int e = tid; e < 77*64; e += 256){
    const int n = e >> 6, c = e & 63;
    kk[n][c] = kbuf[((size_t)bc * 77 + n) * 512 + h*64 + c];
    vv[n][c] = vbuf[((size_t)bc * 77 + n) * 512 + h*64 + c];
  }
  __syncthreads();
  if(tid < 64){
    float m = -1e30f;
    for(int n=0;n<77;n++) m = fmaxf(m, kk[n][tid]);
    float s = 0.f;
    for(int n=0;n<77;n++){ const float e = __expf(kk[n][tid] - m); kk[n][tid] = e; s += e; }
    inv_s[tid] = 1.f / s;
  }
  __syncthreads();
  #pragma unroll
  for(int j=0;j<16;j++){
    const int o = tid + 256*j;
    const int v = o >> 6, k2 = o & 63;
    float a = 0.f;
    for(int n=0;n<77;n++) a += kk[n][k2] * vv[n][v];
    const int pos = ((((k2>>5)*4 + (v>>4))*4 + ((k2>>3)&3))*16 + (v&15))*8 + (k2&7);
    ctxP[((size_t)(bc*8 + h)) * 4096 + pos] = f2bf(a * inv_s[k2]);
  }
}

// ---------------------------------------------------------------------------
// Kernel 3: copy non-conditioned batches
// ---------------------------------------------------------------------------
__global__ void k_copy(const float* __restrict__ in, const int* __restrict__ idx,
                       float* __restrict__ out)
{
  const int b = blockIdx.y;
  bool member = false;
  for(int i=0;i<24;i++) member |= (idx[i] == b);
  if(member) return;
  const float4* s = (const float4*)(in  + (size_t)b * 512 * 4096);
  float4*       d = (float4*)      (out + (size_t)b * 512 * 4096);
  for(int i = blockIdx.x*256 + threadIdx.x; i < 512*4096/4; i += 128*256) d[i] = s[i];
}

// ---------------------------------------------------------------------------
// Kernel 4: fused GEMM on RAW x with LN folded into the epilogue.
//   G = x^T @ (g.Wq); q = rs*G - rs*mu*c2 + c1 + bq; softmax; PV; residual.
// grid (4 ntile, 768 mtile = 24bc x 32 t-tiles), 256 threads (4 waves 2x2).
// LDS: double-buffered Xs (fp32 [32][128]) + Ws (bf16 [128][32]); P aliased.
// ---------------------------------------------------------------------------
__global__ __launch_bounds__(256, 3)
void k_gemm2(const float* __restrict__ input, const int* __restrict__ idx,
             const unsigned short* __restrict__ gWqT, const float2* __restrict__ c12,
             const float* __restrict__ bq, const unsigned short* __restrict__ ctxP,
             float* __restrict__ out)
{
  __shared__ __align__(16) char smem[49152];
  float*          Xs0 = (float*)(smem);
  unsigned short* Ws0 = (unsigned short*)(smem + 16384);
  float*          Xs1 = (float*)(smem + 24576);
  unsigned short* Ws1 = (unsigned short*)(smem + 40960);
  unsigned short* P   = (unsigned short*)(smem);            // [4][64][72] (36864B)
  float*          red = (float*)(smem + 36864);             // [128][2][2]
  float*          mu_s= (float*)(smem + 38912);             // [128]
  float*          rs_s= (float*)(smem + 39424);             // [128]

  const int tid  = threadIdx.x;
  const int lane = tid & 63;
  const int w    = tid >> 6;
  const int col  = lane & 15;
  const int g    = lane >> 4;
  const int wm   = w >> 1, wn = w & 1;
  const int ntile = blockIdx.x, mtile = blockIdx.y;
  const int bc   = mtile >> 5;
  const int tt0  = (mtile & 31) * 128;
  const int b    = idx[bc];
  const int nbase = ntile * 128;
  const char* xbase = (const char*)(input + (size_t)b * 512 * 4096) + (size_t)tt0 * 4;
  const char* wbase = (const char*)gWqT + (size_t)nbase * 1024;

  const int tstat = tid & 127;
  const int hstat = tid >> 7;
  float s1 = 0.f, s2 = 0.f;

  float* Xbuf[2] = {Xs0, Xs1};
  unsigned short* Wbuf[2] = {Ws0, Ws1};

  // ---- staging: 4 gll16 for X (16KB fp32), 2 for W (8KB bf16) ----
  #define STAGE(ks, bi)                                                          \
  {                                                                              \
    _Pragma("unroll")                                                            \
    for(int i=0;i<4;i++){                                                        \
      const int f = tid*16 + i*4096;                                             \
      const int kk_ = f >> 9, oo_ = f & 511;                                     \
      gll16(xbase + (size_t)((ks)*32 + kk_) * 16384 + oo_, (char*)Xbuf[bi] + f); \
    }                                                                            \
    _Pragma("unroll")                                                            \
    for(int i=0;i<2;i++){                                                        \
      const int f = tid*16 + i*4096;                                             \
      const int nn_ = f >> 6, oo_ = f & 63;                                      \
      gll16(wbase + (size_t)nn_ * 1024 + (ks)*64 + oo_, (char*)Wbuf[bi] + f);    \
    }                                                                            \
  }

  f32x4 acc[4][4] = {};

  STAGE(0, 0);
  __syncthreads();

  for(int ks=0; ks<16; ++ks){
    const int cur = ks & 1;
    if(ks < 15) STAGE(ks+1, cur^1);

    const float* X = Xbuf[cur];
    const unsigned short* W = Wbuf[cur];

    // A-frags from raw x (fp32 -> bf16 in regs)
    bf16x8 af[4];
    #pragma unroll
    for(int mt=0; mt<4; ++mt){
      const int t = wm*64 + mt*16 + col;
      union { unsigned short s[8]; bf16x8 v; } u;
      #pragma unroll
      for(int j=0;j<8;++j){
        const float fv = X[(g*8 + j)*128 + t];
        u.s[j] = __bfloat16_as_ushort(__float2bfloat16(fv));
      }
      af[mt] = u.v;
    }
    // B-frags from folded weights
    bf16x8 bfr[4];
    #pragma unroll
    for(int nt=0; nt<4; ++nt)
      bfr[nt] = *(const bf16x8*)(W + (size_t)(wn*64 + nt*16 + col)*32 + g*8);

    #pragma unroll
    for(int mt=0; mt<4; ++mt)
      #pragma unroll
      for(int nt=0; nt<4; ++nt)
        acc[mt][nt] = __builtin_amdgcn_mfma_f32_16x16x32_bf16(af[mt], bfr[nt], acc[mt][nt], 0, 0, 0);

    // LN stats from the staged fp32 tile (exact)
    #pragma unroll
    for(int i=0;i<16;++i){
      const float xv = X[(hstat*16 + i)*128 + tstat];
      s1 += xv; s2 += xv*xv;
    }
    __syncthreads();
  }
  #undef STAGE

  // ---- stats reduce (staging LDS now dead -> reuse region) ----
  red[tstat*4 + hstat*2 + 0] = s1;
  red[tstat*4 + hstat*2 + 1] = s2;
  __syncthreads();
  if(tid < 128){
    const float a = red[tid*4 + 0] + red[tid*4 + 2];
    const float c = red[tid*4 + 1] + red[tid*4 + 3];
    const float mu = a * (1.f/512.f);
    const float var = c * (1.f/512.f) - mu*mu;
    mu_s[tid] = mu;
    rs_s[tid] = rsqrtf(var + LN_EPS);
  }
  __syncthreads();

  // ---- q assembly (LN fold) + per-head feature softmax ----
  float c1b[4], c2v[4];
  #pragma unroll
  for(int nt=0; nt<4; ++nt){
    const int n = nbase + wn*64 + nt*16 + col;
    const float2 cc = c12[n];
    c1b[nt] = cc.x + bq[n];
    c2v[nt] = cc.y;
  }
  #pragma unroll
  for(int mt=0; mt<4; ++mt){
    #pragma unroll
    for(int r=0; r<4; ++r){
      const int t = wm*64 + mt*16 + g*4 + r;
      const float mur = mu_s[t], rsr = rs_s[t];
      const float mrc = rsr * mur;
      float v[4];
      #pragma unroll
      for(int nt=0; nt<4; ++nt)
        v[nt] = rsr*acc[mt][nt][r] - mrc*c2v[nt] + c1b[nt];
      float m = fmaxf(fmaxf(v[0],v[1]), fmaxf(v[2],v[3]));
      m = fmaxf(m, __shfl_xor(m, 1));
      m = fmaxf(m, __shfl_xor(m, 2));
      m = fmaxf(m, __shfl_xor(m, 4));
      m = fmaxf(m, __shfl_xor(m, 8));
      float s = 0.f;
      #pragma unroll
      for(int nt=0; nt<4; ++nt){ v[nt] = __expf(v[nt] - m); s += v[nt]; }
      s += __shfl_xor(s, 1);
      s += __shfl_xor(s, 2);
      s += __shfl_xor(s, 4);
      s += __shfl_xor(s, 8);
      const float inv = 1.f / s;
      #pragma unroll
      for(int nt=0; nt<4; ++nt) acc[mt][nt][r] = v[nt] * inv;
    }
  }

  // ---- P store (wave-private) ----
  unsigned short* Pw = P + w * 64 * 72;
  #pragma unroll
  for(int mt=0; mt<4; ++mt)
    #pragma unroll
    for(int nt=0; nt<4; ++nt)
      #pragma unroll
      for(int r=0; r<4; ++r)
        Pw[(mt*16 + g*4 + r)*72 + nt*16 + col] = f2bf(acc[mt][nt][r]);

  // ---- PV: y[t][v] = sum_k P[t][k] * ctx[k][v] ----
  const int head = ntile*2 + wn;
  const unsigned short* cp = ctxP + (size_t)(bc*8 + head) * 4096;
  f32x4 y[4][4] = {};
  #pragma unroll
  for(int ks2=0; ks2<2; ++ks2){
    bf16x8 pa[4];
    #pragma unroll
    for(int mt=0; mt<4; ++mt)
      pa[mt] = *(const bf16x8*)(Pw + (mt*16 + col)*72 + ks2*32 + g*8);
    bf16x8 cv[4];
    #pragma unroll
    for(int vt=0; vt<4; ++vt)
      cv[vt] = *(const bf16x8*)(cp + (size_t)(((ks2*4 + vt)*4 + g)*16 + col) * 8);
    #pragma unroll
    for(int mt=0; mt<4; ++mt)
      #pragma unroll
      for(int vt=0; vt<4; ++vt)
        y[mt][vt] = __builtin_amdgcn_mfma_f32_16x16x32_bf16(pa[mt], cv[vt], y[mt][vt], 0, 0, 0);
  }

  // ---- residual + store (float4 along t) ----
  const float* xb = input + (size_t)b * 512 * 4096;
  float*       ob = out   + (size_t)b * 512 * 4096;
  #pragma unroll
  for(int mt=0; mt<4; ++mt)
    #pragma unroll
    for(int vt=0; vt<4; ++vt){
      const size_t row = (size_t)(head*64 + vt*16 + col);
      const size_t a = row*4096 + (size_t)(tt0 + wm*64 + mt*16 + g*4);
      const float4 xr = *(const float4*)(xb + a);
      float4 o4;
      o4.x = xr.x + y[mt][vt][0];
      o4.y = xr.y + y[mt][vt][1];
      o4.z = xr.z + y[mt][vt][2];
      o4.w = xr.w + y[mt][vt][3];
      *(float4*)(ob + a) = o4;
    }
}

// ---------------------------------------------------------------------------
extern "C" void kernel_launch(void* const* d_in, const int* in_sizes, int n_in,
                              void* d_out, int out_size, void* d_ws, size_t ws_size,
                              hipStream_t stream)
{
  const float* input = (const float*)d_in[0];
  const float* cond  = (const float*)d_in[1];
  const int*   idx   = (const int*)d_in[2];
  const float* ln_g  = (const float*)d_in[3];
  const float* ln_b  = (const float*)d_in[4];
  const float* tln_g = (const float*)d_in[5];
  const float* tln_b = (const float*)d_in[6];
  const float* Wq    = (const float*)d_in[7];
  const float* bq    = (const float*)d_in[8];
  const float* Wk    = (const float*)d_in[9];
  const float* bk    = (const float*)d_in[10];
  const float* Wv    = (const float*)d_in[11];
  const float* bv    = (const float*)d_in[12];
  float* out = (float*)d_out;
  char*  ws  = (char*)d_ws;

  // workspace layout
  unsigned short* gWqT = (unsigned short*)(ws);                  // 512 KB
  float2*         c12  = (float2*)(ws + 524288);                 // 4 KB
  unsigned short* ctxP = (unsigned short*)(ws + 528384);         // 1.5 MB
  float* kbuf = (float*)(ws + 2101248);                          // 3.61 MB
  float* vbuf = (float*)(ws + 2101248 + 3784704);                // 3.61 MB

  k_prep  <<<dim3(8),       dim3(256), 0, stream>>>(Wq, ln_g, ln_b, gWqT, c12);
  k_condkv<<<dim3(4,5,24),  dim3(256), 0, stream>>>(cond, idx, tln_g, tln_b, Wk, bk, Wv, bv, kbuf, vbuf);
  k_ctx   <<<dim3(8,24),    dim3(256), 0, stream>>>(kbuf, vbuf, ctxP);
  k_copy  <<<dim3(128,32),  dim3(256), 0, stream>>>(input, idx, out);
  k_gemm2 <<<dim3(4,768),   dim3(256), 0, stream>>>(input, idx, gWqT, c12, bq, ctxP, out);
}

// Round 4
// 446.318 us; speedup vs baseline: 1.0079x; 1.0079x over previous
//
#include <hip/hip_runtime.h>
#include <hip/hip_bf16.h>

#define LN_EPS 1e-5f

typedef __attribute__((ext_vector_type(8))) short bf16x8;
typedef __attribute__((ext_vector_type(8))) short s16x8;
typedef __attribute__((ext_vector_type(4))) float f32x4;

__device__ __forceinline__ unsigned short f2bf(float f){
  unsigned u = __builtin_bit_cast(unsigned, f);
  u = (u + 0x7fffu + ((u >> 16) & 1u)) >> 16;
  return (unsigned short)u;
}
__device__ __forceinline__ void gll16(const void* g, void* l){
  __builtin_amdgcn_global_load_lds(
      (const __attribute__((address_space(1))) unsigned int*)(g),
      (__attribute__((address_space(3))) unsigned int*)(l), 16, 0, 0);
}

// ---------------------------------------------------------------------------
// Kernel 0: WqT_swz[n][d ^ slot-swizzle] = bf16(Wq[d][n]).
// Slot swizzle: 16B slots (8 elems) within each 32-elem group XOR'd by
// (n>>1)&3 so that linear gll16 staging + XOR'd ds_read is conflict-free.
// ---------------------------------------------------------------------------
__global__ void k_wqt(const float* __restrict__ Wq, unsigned short* __restrict__ WqT){
  const int tid = blockIdx.x * 256 + threadIdx.x;
  const int d = tid >> 9, n = tid & 511;
  const int swz = (n >> 1) & 3;
  WqT[(size_t)n * 512 + (d ^ (swz << 3))] = f2bf(Wq[(size_t)d * 512 + n]);
}

// ---------------------------------------------------------------------------
// Kernel 1: cond LN + K/V projection (unchanged)
// ---------------------------------------------------------------------------
__global__ void k_condkv(const float* __restrict__ cond, const int* __restrict__ idx,
                         const float* __restrict__ tg, const float* __restrict__ tb,
                         const float* __restrict__ Wk, const float* __restrict__ bk,
                         const float* __restrict__ Wv, const float* __restrict__ bv,
                         float* __restrict__ kbuf, float* __restrict__ vbuf)
{
  __shared__ float cn[16][768];
  const int bc = blockIdx.z, nc = blockIdx.y, dc = blockIdx.x;
  const int b = idx[bc];
  const int n0 = nc * 16;
  int nrows = 77 - n0; if(nrows > 16) nrows = 16;
  const int w = threadIdx.x >> 6, lane = threadIdx.x & 63;

  for(int r = w; r < nrows; r += 4){
    const float* src = cond + ((size_t)b * 77 + n0 + r) * 768;
    float vals[12]; float s1 = 0.f, s2 = 0.f;
    #pragma unroll
    for(int i=0;i<12;i++){ float x = src[lane + i*64]; vals[i]=x; s1+=x; s2+=x*x; }
    #pragma unroll
    for(int off=1; off<64; off<<=1){ s1 += __shfl_xor(s1, off); s2 += __shfl_xor(s2, off); }
    const float mu  = s1 * (1.f/768.f);
    const float var = s2 * (1.f/768.f) - mu*mu;
    const float rs  = rsqrtf(var + LN_EPS);
    #pragma unroll
    for(int i=0;i<12;i++){ const int c2 = lane + i*64; cn[r][c2] = (vals[i]-mu)*rs*tg[c2] + tb[c2]; }
  }
  __syncthreads();

  const int dq = threadIdx.x & 63;
  const int part = threadIdx.x >> 6;
  const float* W    = (dc < 2) ? Wk : Wv;
  const float* bias = (dc < 2) ? bk : bv;
  float* obuf       = (dc < 2) ? kbuf : vbuf;
  const int d0 = (dc & 1) * 256 + dq * 4;

  float acc[4][4] = {};
  for(int i=0;i<768;i++){
    const float4 wv = *(const float4*)(W + (size_t)i * 512 + d0);
    #pragma unroll
    for(int j=0;j<4;j++){
      const float c = cn[part*4 + j][i];
      acc[j][0] += c * wv.x; acc[j][1] += c * wv.y;
      acc[j][2] += c * wv.z; acc[j][3] += c * wv.w;
    }
  }
  #pragma unroll
  for(int j=0;j<4;j++){
    const int r = part*4 + j, n = n0 + r;
    if(r < nrows){
      float4 o;
      o.x = acc[j][0] + bias[d0+0];
      o.y = acc[j][1] + bias[d0+1];
      o.z = acc[j][2] + bias[d0+2];
      o.w = acc[j][3] + bias[d0+3];
      *(float4*)(obuf + ((size_t)bc * 77 + n) * 512 + d0) = o;
    }
  }
}

// ---------------------------------------------------------------------------
// Kernel 2: softmax K over tokens; ctxP packed in MFMA-B-frag order
// pos(k,v) = (((k>>5)*4 + (v>>4))*4 + ((k>>3)&3))*16 + (v&15))*8 + (k&7)
// ---------------------------------------------------------------------------
__global__ void k_ctx(const float* __restrict__ kbuf, const float* __restrict__ vbuf,
                      unsigned short* __restrict__ ctxP)
{
  __shared__ float kk[77][64];
  __shared__ float vv[77][64];
  __shared__ float inv_s[64];
  const int h = blockIdx.x, bc = blockIdx.y;
  const int tid = threadIdx.x;
  for(int e = tid; e < 77*64; e += 256){
    const int n = e >> 6, c = e & 63;
    kk[n][c] = kbuf[((size_t)bc * 77 + n) * 512 + h*64 + c];
    vv[n][c] = vbuf[((size_t)bc * 77 + n) * 512 + h*64 + c];
  }
  __syncthreads();
  if(tid < 64){
    float m = -1e30f;
    for(int n=0;n<77;n++) m = fmaxf(m, kk[n][tid]);
    float s = 0.f;
    for(int n=0;n<77;n++){ const float e = __expf(kk[n][tid] - m); kk[n][tid] = e; s += e; }
    inv_s[tid] = 1.f / s;
  }
  __syncthreads();
  #pragma unroll
  for(int j=0;j<16;j++){
    const int o = tid + 256*j;
    const int v = o >> 6, k2 = o & 63;
    float a = 0.f;
    for(int n=0;n<77;n++) a += kk[n][k2] * vv[n][v];
    const int pos = ((((k2>>5)*4 + (v>>4))*4 + ((k2>>3)&3))*16 + (v&15))*8 + (k2&7);
    ctxP[((size_t)(bc*8 + h)) * 4096 + pos] = f2bf(a * inv_s[k2]);
  }
}

// ---------------------------------------------------------------------------
// Kernel 3: copy non-conditioned batches
// ---------------------------------------------------------------------------
__global__ void k_copy(const float* __restrict__ in, const int* __restrict__ idx,
                       float* __restrict__ out)
{
  const int b = blockIdx.y;
  bool member = false;
  for(int i=0;i<24;i++) member |= (idx[i] == b);
  if(member) return;
  const float4* s = (const float4*)(in  + (size_t)b * 512 * 4096);
  float4*       d = (float4*)      (out + (size_t)b * 512 * 4096);
  for(int i = blockIdx.x*256 + threadIdx.x; i < 512*4096/4; i += 128*256) d[i] = s[i];
}

// ---------------------------------------------------------------------------
// Kernel 4: LN + transpose + bf16, slot-swizzled output xT[bc][t][d^swz]
// ---------------------------------------------------------------------------
__global__ __launch_bounds__(256, 2)
void k_lnt(const float* __restrict__ input, const int* __restrict__ idx,
           const float* __restrict__ ln_g, const float* __restrict__ ln_b,
           unsigned short* __restrict__ xT)
{
  __shared__ float buf[32][516];
  __shared__ float red1[32][8], red2[32][8];
  __shared__ float mu_s[32], rs_s[32];
  __shared__ float gbuf[512], bbuf[512];

  const int tid = threadIdx.x;
  const int bc = blockIdx.y;
  const int b  = idx[bc];
  const int t0 = blockIdx.x * 32;
  const float* xb = input + (size_t)b * (512*4096) + t0;

  *(float2*)&gbuf[tid*2] = *(const float2*)&ln_g[tid*2];
  *(float2*)&bbuf[tid*2] = *(const float2*)&ln_b[tid*2];

  {
    const int p  = tid & 7;
    const int dg = tid >> 3;
    #pragma unroll
    for(int i=0;i<16;i++){
      const int d = dg + i*32;
      const float4 x = *(const float4*)(xb + (size_t)d * 4096 + p*4);
      buf[p*4+0][d] = x.x; buf[p*4+1][d] = x.y;
      buf[p*4+2][d] = x.z; buf[p*4+3][d] = x.w;
    }
  }
  __syncthreads();

  {
    const int t = tid & 31, part = tid >> 5;
    float s1 = 0.f, s2 = 0.f;
    #pragma unroll
    for(int i=0;i<16;i++){
      const float4 v = *(const float4*)&buf[t][part*64 + i*4];
      s1 += v.x+v.y+v.z+v.w;
      s2 += v.x*v.x + v.y*v.y + v.z*v.z + v.w*v.w;
    }
    red1[t][part] = s1; red2[t][part] = s2;
  }
  __syncthreads();
  if(tid < 32){
    float a = 0.f, c = 0.f;
    #pragma unroll
    for(int p=0;p<8;p++){ a += red1[tid][p]; c += red2[tid][p]; }
    const float mu  = a * (1.f/512.f);
    const float var = c * (1.f/512.f) - mu*mu;
    mu_s[tid] = mu; rs_s[tid] = rsqrtf(var + LN_EPS);
  }
  __syncthreads();

  {
    const int c  = tid & 7;
    const int tt = tid >> 3;
    const float mu = mu_s[tt], rs = rs_s[tt];
    const int swz = (tt >> 1) & 3;           // bits 1,2 of global t (t0 % 32 == 0)
    unsigned short* orow = xT + ((size_t)bc*4096 + t0 + tt) * 512;
    #pragma unroll
    for(int j=0;j<8;j++){
      const int d0 = c*8 + j*64;
      const float4 a  = *(const float4*)&buf[tt][d0];
      const float4 b4 = *(const float4*)&buf[tt][d0+4];
      const float4 g0 = *(const float4*)&gbuf[d0];
      const float4 g1 = *(const float4*)&gbuf[d0+4];
      const float4 h0 = *(const float4*)&bbuf[d0];
      const float4 h1 = *(const float4*)&bbuf[d0+4];
      s16x8 o;
      o[0] = (short)f2bf((a.x -mu)*rs*g0.x + h0.x);
      o[1] = (short)f2bf((a.y -mu)*rs*g0.y + h0.y);
      o[2] = (short)f2bf((a.z -mu)*rs*g0.z + h0.z);
      o[3] = (short)f2bf((a.w -mu)*rs*g0.w + h0.w);
      o[4] = (short)f2bf((b4.x-mu)*rs*g1.x + h1.x);
      o[5] = (short)f2bf((b4.y-mu)*rs*g1.y + h1.y);
      o[6] = (short)f2bf((b4.z-mu)*rs*g1.z + h1.z);
      o[7] = (short)f2bf((b4.w-mu)*rs*g1.w + h1.w);
      *(s16x8*)(orow + (d0 ^ (swz << 3))) = o;   // slot-swizzled store
    }
  }
}

// ---------------------------------------------------------------------------
// Kernel 5: 128x128 MFMA GEMM (q = xT @ WqT^T), double-buffered with raw
// s_barrier + vmcnt(0) (loads stay in flight over compute), swizzled LDS,
// fused softmax / PV / float4 residual epilogue.
// grid (4 ntile, 768 mtile), 256 threads (4 waves, 2x2).
// ---------------------------------------------------------------------------
__global__ __launch_bounds__(256, 4)
void k_gemm3(const float* __restrict__ input, const int* __restrict__ idx,
             const unsigned short* __restrict__ xT, const unsigned short* __restrict__ WqT,
             const float* __restrict__ bq, const unsigned short* __restrict__ ctxP,
             float* __restrict__ out)
{
  __shared__ __align__(16) char smem[36864];
  char* Ab[2] = { smem,         smem + 16384 };
  char* Bb[2] = { smem + 8192,  smem + 24576 };
  unsigned short* P = (unsigned short*)smem;   // [4][64][72] aliased after K-loop

  const int tid  = threadIdx.x;
  const int lane = tid & 63;
  const int w    = tid >> 6;
  const int col  = lane & 15;
  const int g    = lane >> 4;
  const int wm   = w >> 1, wn = w & 1;
  const int ntile = blockIdx.x, mtile = blockIdx.y;
  const int bc   = mtile >> 5;
  const int tt0  = (mtile & 31) * 128;
  const int b    = idx[bc];
  const int nbase = ntile * 128;
  const char* xTb = (const char*)xT + ((size_t)bc*4096 + tt0) * 1024;
  const char* wTb = (const char*)WqT + (size_t)nbase * 1024;

  const int f0 = tid * 16;          // byte in 8KB half, issue 0
  const int f1 = f0 + 4096;         // issue 1
  const int r0 = f0 >> 6, o0 = f0 & 63;
  const int r1 = f1 >> 6, o1 = f1 & 63;

  #define STAGE(ks, bi)                                          \
  {                                                              \
    gll16(xTb + (size_t)r0*1024 + (ks)*64 + o0, Ab[bi] + f0);    \
    gll16(xTb + (size_t)r1*1024 + (ks)*64 + o1, Ab[bi] + f1);    \
    gll16(wTb + (size_t)r0*1024 + (ks)*64 + o0, Bb[bi] + f0);    \
    gll16(wTb + (size_t)r1*1024 + (ks)*64 + o1, Bb[bi] + f1);    \
  }

  f32x4 acc[4][4] = {};

  // swizzled frag byte offsets (slot = g ^ ((row>>1)&3))
  int offA[4], offB[4];
  #pragma unroll
  for(int mt=0; mt<4; ++mt){
    const int rowA = wm*64 + mt*16 + col;
    offA[mt] = rowA*64 + ((g ^ ((rowA>>1)&3)) << 4);
    const int rowB = wn*64 + mt*16 + col;
    offB[mt] = rowB*64 + ((g ^ ((rowB>>1)&3)) << 4);
  }

  STAGE(0, 0);
  asm volatile("s_waitcnt vmcnt(0)" ::: "memory");
  __builtin_amdgcn_s_barrier();

  for(int ks=0; ks<16; ++ks){
    const int cur = ks & 1;
    if(ks < 15) STAGE(ks+1, cur^1);

    bf16x8 af[4], bfr[4];
    #pragma unroll
    for(int mt=0; mt<4; ++mt) af[mt]  = *(const bf16x8*)(Ab[cur] + offA[mt]);
    #pragma unroll
    for(int nt=0; nt<4; ++nt) bfr[nt] = *(const bf16x8*)(Bb[cur] + offB[nt]);
    #pragma unroll
    for(int mt=0; mt<4; ++mt)
      #pragma unroll
      for(int nt=0; nt<4; ++nt)
        acc[mt][nt] = __builtin_amdgcn_mfma_f32_16x16x32_bf16(af[mt], bfr[nt], acc[mt][nt], 0, 0, 0);

    asm volatile("s_waitcnt vmcnt(0)" ::: "memory");
    __builtin_amdgcn_s_barrier();
  }
  #undef STAGE

  // ---- bias + per-head feature softmax (wave owns one head) ----
  #pragma unroll
  for(int mt=0; mt<4; ++mt){
    #pragma unroll
    for(int nt=0; nt<4; ++nt){
      const float bqv = bq[nbase + wn*64 + nt*16 + col];
      #pragma unroll
      for(int r=0;r<4;++r) acc[mt][nt][r] += bqv;
    }
    #pragma unroll
    for(int r=0;r<4;++r){
      float m = fmaxf(fmaxf(acc[mt][0][r],acc[mt][1][r]), fmaxf(acc[mt][2][r],acc[mt][3][r]));
      m = fmaxf(m, __shfl_xor(m, 1));
      m = fmaxf(m, __shfl_xor(m, 2));
      m = fmaxf(m, __shfl_xor(m, 4));
      m = fmaxf(m, __shfl_xor(m, 8));
      float s = 0.f;
      #pragma unroll
      for(int q=0;q<4;++q){
        const float e = __expf(acc[mt][q][r] - m);
        acc[mt][q][r] = e; s += e;
      }
      s += __shfl_xor(s, 1);
      s += __shfl_xor(s, 2);
      s += __shfl_xor(s, 4);
      s += __shfl_xor(s, 8);
      const float inv = 1.f / s;
      #pragma unroll
      for(int q=0;q<4;++q) acc[mt][q][r] *= inv;
    }
  }

  // ---- P store (wave-private region; staging LDS dead after last barrier) ----
  unsigned short* Pw = P + w * 64 * 72;
  #pragma unroll
  for(int mt=0; mt<4; ++mt)
    #pragma unroll
    for(int nt=0; nt<4; ++nt)
      #pragma unroll
      for(int r=0; r<4; ++r)
        Pw[(mt*16 + g*4 + r)*72 + nt*16 + col] = f2bf(acc[mt][nt][r]);

  // ---- PV: y[t][v] = sum_k P[t][k] * ctx[k][v] ----
  const int head = ntile*2 + wn;
  const unsigned short* cp = ctxP + (size_t)(bc*8 + head) * 4096;
  f32x4 y[4][4] = {};
  #pragma unroll
  for(int ks2=0; ks2<2; ++ks2){
    bf16x8 pa[4];
    #pragma unroll
    for(int mt=0; mt<4; ++mt)
      pa[mt] = *(const bf16x8*)(Pw + (mt*16 + col)*72 + ks2*32 + g*8);
    bf16x8 cv[4];
    #pragma unroll
    for(int vt=0; vt<4; ++vt)
      cv[vt] = *(const bf16x8*)(cp + (size_t)(((ks2*4 + vt)*4 + g)*16 + col) * 8);
    #pragma unroll
    for(int mt=0; mt<4; ++mt)
      #pragma unroll
      for(int vt=0; vt<4; ++vt)
        y[mt][vt] = __builtin_amdgcn_mfma_f32_16x16x32_bf16(pa[mt], cv[vt], y[mt][vt], 0, 0, 0);
  }

  // ---- residual + store (float4 along t) ----
  const float* xb = input + (size_t)b * 512 * 4096;
  float*       ob = out   + (size_t)b * 512 * 4096;
  #pragma unroll
  for(int mt=0; mt<4; ++mt)
    #pragma unroll
    for(int vt=0; vt<4; ++vt){
      const size_t row = (size_t)(head*64 + vt*16 + col);
      const size_t a = row*4096 + (size_t)(tt0 + wm*64 + mt*16 + g*4);
      const float4 xr = *(const float4*)(xb + a);
      float4 o4;
      o4.x = xr.x + y[mt][vt][0];
      o4.y = xr.y + y[mt][vt][1];
      o4.z = xr.z + y[mt][vt][2];
      o4.w = xr.w + y[mt][vt][3];
      *(float4*)(ob + a) = o4;
    }
}

// ---------------------------------------------------------------------------
extern "C" void kernel_launch(void* const* d_in, const int* in_sizes, int n_in,
                              void* d_out, int out_size, void* d_ws, size_t ws_size,
                              hipStream_t stream)
{
  const float* input = (const float*)d_in[0];
  const float* cond  = (const float*)d_in[1];
  const int*   idx   = (const int*)d_in[2];
  const float* ln_g  = (const float*)d_in[3];
  const float* ln_b  = (const float*)d_in[4];
  const float* tln_g = (const float*)d_in[5];
  const float* tln_b = (const float*)d_in[6];
  const float* Wq    = (const float*)d_in[7];
  const float* bq    = (const float*)d_in[8];
  const float* Wk    = (const float*)d_in[9];
  const float* bk    = (const float*)d_in[10];
  const float* Wv    = (const float*)d_in[11];
  const float* bv    = (const float*)d_in[12];
  float* out = (float*)d_out;
  char*  ws  = (char*)d_ws;

  unsigned short* WqT  = (unsigned short*)(ws);                  // 512 KB
  unsigned short* ctxP = (unsigned short*)(ws + 524288);         // 1.5 MB
  float* kbuf = (float*)(ws + 2097152);                          // 3.61 MB
  float* vbuf = (float*)(ws + 2097152 + 3784704);                // 3.61 MB
  unsigned short* xT = (unsigned short*)(ws + 2097152 + 2*3784704); // 96 MB

  k_wqt   <<<dim3(1024),    dim3(256), 0, stream>>>(Wq, WqT);
  k_condkv<<<dim3(4,5,24),  dim3(256), 0, stream>>>(cond, idx, tln_g, tln_b, Wk, bk, Wv, bv, kbuf, vbuf);
  k_ctx   <<<dim3(8,24),    dim3(256), 0, stream>>>(kbuf, vbuf, ctxP);
  k_copy  <<<dim3(128,32),  dim3(256), 0, stream>>>(input, idx, out);
  k_lnt   <<<dim3(128,24),  dim3(256), 0, stream>>>(input, idx, ln_g, ln_b, xT);
  k_gemm3 <<<dim3(4,768),   dim3(256), 0, stream>>>(input, idx, xT, WqT, bq, ctxP, out);
}

// Round 5
// 427.623 us; speedup vs baseline: 1.0519x; 1.0437x over previous
//
#include <hip/hip_runtime.h>

#define LN_EPS 1e-5f

typedef __attribute__((ext_vector_type(8))) short bf16x8;
typedef __attribute__((ext_vector_type(4))) float f32x4;

__device__ __forceinline__ unsigned short f2bf(float f){
  unsigned u = __builtin_bit_cast(unsigned, f);
  u = (u + 0x7fffu + ((u >> 16) & 1u)) >> 16;
  return (unsigned short)u;
}
__device__ __forceinline__ float bf2f(unsigned short h){
  unsigned u = ((unsigned)h) << 16;
  return __builtin_bit_cast(float, u);
}
__device__ __forceinline__ void gll16(const void* g, void* l){
  __builtin_amdgcn_global_load_lds(
      (const __attribute__((address_space(1))) unsigned int*)(g),
      (__attribute__((address_space(3))) unsigned int*)(l), 16, 0, 0);
}

// ---------------------------------------------------------------------------
// Kernel 0: fold LN gamma into Wq, slot-swizzled store.
//  gWqT[n][d ^ ((n>>1)&3)<<3] = bf16(g[d]*Wq[d][n])
//  c12[n] = { sum_d b[d]*Wq[d][n],  sum_d bf16(g*W)[d][n] }
// ---------------------------------------------------------------------------
__global__ void k_prep(const float* __restrict__ Wq, const float* __restrict__ ln_g,
                       const float* __restrict__ ln_b, const float* __restrict__ bq,
                       unsigned short* __restrict__ gWqT, float2* __restrict__ c12)
{
  __shared__ float r1[64][4], r2[64][4];
  const int tid = threadIdx.x;
  const int n0 = blockIdx.x * 64;
  const int c = tid & 63, q = tid >> 6;
  const int n = n0 + c;
  const int swz = (n >> 1) & 3;
  float c1p = 0.f, c2p = 0.f;
  for(int i=0;i<128;i+=4){
    ushort4 pk;
    unsigned short* pp = (unsigned short*)&pk;
    #pragma unroll
    for(int j=0;j<4;j++){
      const int d = q*128 + i + j;
      const float wv = Wq[(size_t)d*512 + n];
      const unsigned short hb = f2bf(ln_g[d] * wv);
      pp[j] = hb;
      c2p += bf2f(hb);
      c1p += ln_b[d] * wv;
    }
    *(ushort4*)(gWqT + (size_t)n*512 + ((q*128 + i) ^ (swz << 3))) = pk;
  }
  r1[c][q] = c1p; r2[c][q] = c2p;
  __syncthreads();
  if(q == 0){
    float a = 0.f, b2 = 0.f;
    #pragma unroll
    for(int j=0;j<4;j++){ a += r1[c][j]; b2 += r2[c][j]; }
    c12[n] = make_float2(a + bq[n], b2);
  }
}

// ---------------------------------------------------------------------------
// Kernel 1: cond LN + K/V projection (unchanged, validated)
// ---------------------------------------------------------------------------
__global__ void k_condkv(const float* __restrict__ cond, const int* __restrict__ idx,
                         const float* __restrict__ tg, const float* __restrict__ tb,
                         const float* __restrict__ Wk, const float* __restrict__ bk,
                         const float* __restrict__ Wv, const float* __restrict__ bv,
                         float* __restrict__ kbuf, float* __restrict__ vbuf)
{
  __shared__ float cn[16][768];
  const int bc = blockIdx.z, nc = blockIdx.y, dc = blockIdx.x;
  const int b = idx[bc];
  const int n0 = nc * 16;
  int nrows = 77 - n0; if(nrows > 16) nrows = 16;
  const int w = threadIdx.x >> 6, lane = threadIdx.x & 63;

  for(int r = w; r < nrows; r += 4){
    const float* src = cond + ((size_t)b * 77 + n0 + r) * 768;
    float vals[12]; float s1 = 0.f, s2 = 0.f;
    #pragma unroll
    for(int i=0;i<12;i++){ float x = src[lane + i*64]; vals[i]=x; s1+=x; s2+=x*x; }
    #pragma unroll
    for(int off=1; off<64; off<<=1){ s1 += __shfl_xor(s1, off); s2 += __shfl_xor(s2, off); }
    const float mu  = s1 * (1.f/768.f);
    const float var = s2 * (1.f/768.f) - mu*mu;
    const float rs  = rsqrtf(var + LN_EPS);
    #pragma unroll
    for(int i=0;i<12;i++){ const int c2 = lane + i*64; cn[r][c2] = (vals[i]-mu)*rs*tg[c2] + tb[c2]; }
  }
  __syncthreads();

  const int dq = threadIdx.x & 63;
  const int part = threadIdx.x >> 6;
  const float* W    = (dc < 2) ? Wk : Wv;
  const float* bias = (dc < 2) ? bk : bv;
  float* obuf       = (dc < 2) ? kbuf : vbuf;
  const int d0 = (dc & 1) * 256 + dq * 4;

  float acc[4][4] = {};
  for(int i=0;i<768;i++){
    const float4 wv = *(const float4*)(W + (size_t)i * 512 + d0);
    #pragma unroll
    for(int j=0;j<4;j++){
      const float c = cn[part*4 + j][i];
      acc[j][0] += c * wv.x; acc[j][1] += c * wv.y;
      acc[j][2] += c * wv.z; acc[j][3] += c * wv.w;
    }
  }
  #pragma unroll
  for(int j=0;j<4;j++){
    const int r = part*4 + j, n = n0 + r;
    if(r < nrows){
      float4 o;
      o.x = acc[j][0] + bias[d0+0];
      o.y = acc[j][1] + bias[d0+1];
      o.z = acc[j][2] + bias[d0+2];
      o.w = acc[j][3] + bias[d0+3];
      *(float4*)(obuf + ((size_t)bc * 77 + n) * 512 + d0) = o;
    }
  }
}

// ---------------------------------------------------------------------------
// Kernel 2: softmax K over tokens; ctxP packed in MFMA-B-frag order
// ---------------------------------------------------------------------------
__global__ void k_ctx(const float* __restrict__ kbuf, const float* __restrict__ vbuf,
                      unsigned short* __restrict__ ctxP)
{
  __shared__ float kk[77][64];
  __shared__ float vv[77][64];
  __shared__ float inv_s[64];
  const int h = blockIdx.x, bc = blockIdx.y;
  const int tid = threadIdx.x;
  for(int e = tid; e < 77*64; e += 256){
    const int n = e >> 6, c = e & 63;
    kk[n][c] = kbuf[((size_t)bc * 77 + n) * 512 + h*64 + c];
    vv[n][c] = vbuf[((size_t)bc * 77 + n) * 512 + h*64 + c];
  }
  __syncthreads();
  if(tid < 64){
    float m = -1e30f;
    for(int n=0;n<77;n++) m = fmaxf(m, kk[n][tid]);
    float s = 0.f;
    for(int n=0;n<77;n++){ const float e = __expf(kk[n][tid] - m); kk[n][tid] = e; s += e; }
    inv_s[tid] = 1.f / s;
  }
  __syncthreads();
  #pragma unroll
  for(int j=0;j<16;j++){
    const int o = tid + 256*j;
    const int v = o >> 6, k2 = o & 63;
    float a = 0.f;
    for(int n=0;n<77;n++) a += kk[n][k2] * vv[n][v];
    const int pos = ((((k2>>5)*4 + (v>>4))*4 + ((k2>>3)&3))*16 + (v&15))*8 + (k2&7);
    ctxP[((size_t)(bc*8 + h)) * 4096 + pos] = f2bf(a * inv_s[k2]);
  }
}

// ---------------------------------------------------------------------------
// Kernel 3: THE fused kernel. Raw x in, out. LN folded via
//   q = rs*G - rs*mu*c2 + (c1+bq),  G = bf(x)^T @ bf(g.Wq)
// grid (2 ntile, 1024): mtile<768 => gemm block 128t x 256n (24bc x 32 t-tiles)
//                        mtile>=768 => copy blocks for non-cond batches.
// 256 threads, 4 waves (2x2), wave tile 64t x 128n (2 heads).
// X staged reg->bf16 micro-transpose (4t x 4k/thread) into swizzled LDS;
// W staged linear gll16 from pre-swizzled gWqT.
// ---------------------------------------------------------------------------
__global__ __launch_bounds__(256, 2)
void k_fused(const float* __restrict__ input, const int* __restrict__ idx,
             const unsigned short* __restrict__ gWqT, const float2* __restrict__ c12,
             const unsigned short* __restrict__ ctxP, float* __restrict__ out)
{
  const int ntile = blockIdx.x;
  const int mtile = blockIdx.y;
  const int tid = threadIdx.x;

  if(mtile >= 768){
    // ---- copy path for the 8 non-conditioned batches ----
    const int cid = (mtile - 768)*2 + ntile;   // 0..511
    const int nb = cid >> 6, chunk = cid & 63;
    int cnt = 0, bsel = 0;
    for(int b2 = 0; b2 < 32; ++b2){
      bool member = false;
      #pragma unroll
      for(int i2 = 0; i2 < 24; ++i2) member |= (idx[i2] == b2);
      if(!member){ if(cnt == nb) bsel = b2; ++cnt; }
    }
    const float4* s = (const float4*)(input + (size_t)bsel * 2097152) + chunk*8192;
    float4*       d = (float4*)      (out   + (size_t)bsel * 2097152) + chunk*8192;
    #pragma unroll
    for(int i = 0; i < 32; ++i) d[i*256 + tid] = s[i*256 + tid];
    return;
  }

  __shared__ __align__(16) char smem[50176];
  char* const Xb0 = smem;            // [128][32] bf16 swizzled = 8KB
  char* const Wb0 = smem + 8192;     // [256][32] bf16 swizzled = 16KB
  char* const Xb1 = smem + 24576;
  char* const Wb1 = smem + 32768;
  unsigned short* const P = (unsigned short*)smem;  // [4][64][72] = 36864B aliased
  float* const mu_s = (float*)(smem + 49152);       // [128]
  float* const rs_s = (float*)(smem + 49664);       // [128]

  const int lane = tid & 63, w = tid >> 6;
  const int col = lane & 15, g = lane >> 4;
  const int wm = w >> 1, wn = w & 1;
  const int bc = mtile >> 5, b = idx[bc];
  const int t0 = (mtile & 31) * 128;
  const int nbase = ntile * 256;
  const float* xb = input + (size_t)b * 2097152;
  const char* wTb = (const char*)gWqT + (size_t)nbase * 1024;

  // staging decomposition: thread owns a 4t x 4k micro-block
  const int tq = tid >> 3;           // t-local = tq*4 .. +3
  const int kb = tid & 7;            // k = kb*4 .. +3 (within BK=32)
  const float* xsrc = xb + (size_t)(kb*4) * 4096 + t0 + tq*4;

  // X LDS write byte offsets (swizzle: slot16 ^= t&3; t&3 == j)
  int wx[4];
  #pragma unroll
  for(int j=0;j<4;j++)
    wx[j] = (tq*4 + j)*64 + ((((kb>>1) ^ j) & 3) << 4) + ((kb & 1) << 3);

  // frag read byte offsets
  int offA[4], offB[8];
  #pragma unroll
  for(int mt=0; mt<4; ++mt){
    const int rowA = wm*64 + mt*16 + col;
    offA[mt] = rowA*64 + ((g ^ (rowA & 3)) << 4);
  }
  #pragma unroll
  for(int nt=0; nt<8; ++nt){
    const int rowB = wn*128 + nt*16 + col;
    offB[nt] = rowB*64 + ((g ^ ((rowB >> 1) & 3)) << 4);
  }

  const int fW = tid * 16;

  #define STAGEW(ks, Wdst)                                                \
  { _Pragma("unroll")                                                     \
    for(int i=0;i<4;i++){                                                 \
      const int f = fW + i*4096;                                          \
      gll16(wTb + (size_t)(f>>6)*1024 + (ks)*64 + (f&63), (Wdst) + f);    \
    } }
  #define LOADX(xr, ks)                                                   \
  { _Pragma("unroll")                                                     \
    for(int j=0;j<4;j++) xr[j] = *(const float4*)(xsrc + (size_t)((ks)*32 + j) * 4096); }
  #define PUTX(xr, Xdst)                                                  \
  { *(ushort4*)((Xdst) + wx[0]) = make_ushort4(f2bf(xr[0].x), f2bf(xr[1].x), f2bf(xr[2].x), f2bf(xr[3].x)); \
    *(ushort4*)((Xdst) + wx[1]) = make_ushort4(f2bf(xr[0].y), f2bf(xr[1].y), f2bf(xr[2].y), f2bf(xr[3].y)); \
    *(ushort4*)((Xdst) + wx[2]) = make_ushort4(f2bf(xr[0].z), f2bf(xr[1].z), f2bf(xr[2].z), f2bf(xr[3].z)); \
    *(ushort4*)((Xdst) + wx[3]) = make_ushort4(f2bf(xr[0].w), f2bf(xr[1].w), f2bf(xr[2].w), f2bf(xr[3].w)); }
  #define STATS(xr)                                                       \
  { s1[0] += xr[0].x + xr[1].x + xr[2].x + xr[3].x;                       \
    s2[0] += xr[0].x*xr[0].x + xr[1].x*xr[1].x + xr[2].x*xr[2].x + xr[3].x*xr[3].x; \
    s1[1] += xr[0].y + xr[1].y + xr[2].y + xr[3].y;                       \
    s2[1] += xr[0].y*xr[0].y + xr[1].y*xr[1].y + xr[2].y*xr[2].y + xr[3].y*xr[3].y; \
    s1[2] += xr[0].z + xr[1].z + xr[2].z + xr[3].z;                       \
    s2[2] += xr[0].z*xr[0].z + xr[1].z*xr[1].z + xr[2].z*xr[2].z + xr[3].z*xr[3].z; \
    s1[3] += xr[0].w + xr[1].w + xr[2].w + xr[3].w;                       \
    s2[3] += xr[0].w*xr[0].w + xr[1].w*xr[1].w + xr[2].w*xr[2].w + xr[3].w*xr[3].w; }

  f32x4 acc[4][8] = {};
  float s1[4] = {0,0,0,0}, s2[4] = {0,0,0,0};

  {
    float4 xr[4];
    LOADX(xr, 0);
    STAGEW(0, Wb0);
    PUTX(xr, Xb0);
    STATS(xr);
  }
  __syncthreads();

  for(int ks = 0; ks < 16; ++ks){
    char* const Xc = (ks & 1) ? Xb1 : Xb0;
    char* const Wc = (ks & 1) ? Wb1 : Wb0;
    char* const Xn = (ks & 1) ? Xb0 : Xb1;
    char* const Wn = (ks & 1) ? Wb0 : Wb1;
    float4 xn[4];
    if(ks < 15){ LOADX(xn, ks+1); STAGEW(ks+1, Wn); }

    bf16x8 af[4], bfr[8];
    #pragma unroll
    for(int mt=0; mt<4; ++mt) af[mt]  = *(const bf16x8*)(Xc + offA[mt]);
    #pragma unroll
    for(int nt=0; nt<8; ++nt) bfr[nt] = *(const bf16x8*)(Wc + offB[nt]);
    #pragma unroll
    for(int mt=0; mt<4; ++mt)
      #pragma unroll
      for(int nt=0; nt<8; ++nt)
        acc[mt][nt] = __builtin_amdgcn_mfma_f32_16x16x32_bf16(af[mt], bfr[nt], acc[mt][nt], 0, 0, 0);

    if(ks < 15){ PUTX(xn, Xn); STATS(xn); }
    __syncthreads();
  }
  #undef STAGEW
  #undef LOADX
  #undef PUTX
  #undef STATS

  // ---- LN stats reduce over kb lanes (t owned by exactly one 8-lane group) ----
  #pragma unroll
  for(int j=0;j<4;j++){
    #pragma unroll
    for(int off=1; off<8; off<<=1){
      s1[j] += __shfl_xor(s1[j], off);
      s2[j] += __shfl_xor(s2[j], off);
    }
  }
  if(kb == 0){
    #pragma unroll
    for(int j=0;j<4;j++){
      const int t = tq*4 + j;
      const float mu  = s1[j] * (1.f/512.f);
      const float var = s2[j] * (1.f/512.f) - mu*mu;
      mu_s[t] = mu;
      rs_s[t] = rsqrtf(var + LN_EPS);
    }
  }
  __syncthreads();

  // ---- LN fold + per-head feature softmax ----
  float c1b[8], c2v[8];
  #pragma unroll
  for(int nt=0; nt<8; ++nt){
    const float2 cc = c12[nbase + wn*128 + nt*16 + col];
    c1b[nt] = cc.x;     // already includes bq
    c2v[nt] = cc.y;
  }
  #pragma unroll
  for(int mt=0; mt<4; ++mt){
    #pragma unroll
    for(int r=0; r<4; ++r){
      const int tl = wm*64 + mt*16 + g*4 + r;
      const float rsr = rs_s[tl];
      const float mrc = rsr * mu_s[tl];
      float v[8];
      #pragma unroll
      for(int nt=0; nt<8; ++nt)
        v[nt] = rsr*acc[mt][nt][r] - mrc*c2v[nt] + c1b[nt];
      #pragma unroll
      for(int hh=0; hh<2; ++hh){
        float m = fmaxf(fmaxf(v[hh*4+0],v[hh*4+1]), fmaxf(v[hh*4+2],v[hh*4+3]));
        m = fmaxf(m, __shfl_xor(m, 1));
        m = fmaxf(m, __shfl_xor(m, 2));
        m = fmaxf(m, __shfl_xor(m, 4));
        m = fmaxf(m, __shfl_xor(m, 8));
        float s = 0.f;
        float e[4];
        #pragma unroll
        for(int q2=0;q2<4;++q2){ e[q2] = __expf(v[hh*4+q2] - m); s += e[q2]; }
        s += __shfl_xor(s, 1);
        s += __shfl_xor(s, 2);
        s += __shfl_xor(s, 4);
        s += __shfl_xor(s, 8);
        const float inv = 1.f / s;
        #pragma unroll
        for(int q2=0;q2<4;++q2) acc[mt][hh*4+q2][r] = e[q2] * inv;
      }
    }
  }

  // ---- per head: P -> LDS (wave-private), PV MFMA, residual + float4 store ----
  unsigned short* const Pw = P + w * (64*72);
  float* const ob = out + (size_t)b * 2097152;
  #pragma unroll
  for(int hh=0; hh<2; ++hh){
    #pragma unroll
    for(int mt=0; mt<4; ++mt)
      #pragma unroll
      for(int ntl=0; ntl<4; ++ntl)
        #pragma unroll
        for(int r=0; r<4; ++r)
          Pw[(mt*16 + g*4 + r)*72 + ntl*16 + col] = f2bf(acc[mt][hh*4+ntl][r]);

    const int head = ntile*4 + wn*2 + hh;
    const unsigned short* cp = ctxP + (size_t)(bc*8 + head) * 4096;
    f32x4 y[4][4] = {};
    #pragma unroll
    for(int ks2=0; ks2<2; ++ks2){
      bf16x8 pa[4];
      #pragma unroll
      for(int mt=0; mt<4; ++mt)
        pa[mt] = *(const bf16x8*)(Pw + (mt*16 + col)*72 + ks2*32 + g*8);
      bf16x8 cv[4];
      #pragma unroll
      for(int vt=0; vt<4; ++vt)
        cv[vt] = *(const bf16x8*)(cp + (size_t)(((ks2*4 + vt)*4 + g)*16 + col) * 8);
      #pragma unroll
      for(int mt=0; mt<4; ++mt)
        #pragma unroll
        for(int vt=0; vt<4; ++vt)
          y[mt][vt] = __builtin_amdgcn_mfma_f32_16x16x32_bf16(pa[mt], cv[vt], y[mt][vt], 0, 0, 0);
    }
    #pragma unroll
    for(int mt=0; mt<4; ++mt)
      #pragma unroll
      for(int vt=0; vt<4; ++vt){
        const size_t a = (size_t)(head*64 + vt*16 + col)*4096
                       + (size_t)(t0 + wm*64 + mt*16 + g*4);
        const float4 xr4 = *(const float4*)(xb + a);
        float4 o4;
        o4.x = xr4.x + y[mt][vt][0];
        o4.y = xr4.y + y[mt][vt][1];
        o4.z = xr4.z + y[mt][vt][2];
        o4.w = xr4.w + y[mt][vt][3];
        *(float4*)(ob + a) = o4;
      }
  }
}

// ---------------------------------------------------------------------------
extern "C" void kernel_launch(void* const* d_in, const int* in_sizes, int n_in,
                              void* d_out, int out_size, void* d_ws, size_t ws_size,
                              hipStream_t stream)
{
  const float* input = (const float*)d_in[0];
  const float* cond  = (const float*)d_in[1];
  const int*   idx   = (const int*)d_in[2];
  const float* ln_g  = (const float*)d_in[3];
  const float* ln_b  = (const float*)d_in[4];
  const float* tln_g = (const float*)d_in[5];
  const float* tln_b = (const float*)d_in[6];
  const float* Wq    = (const float*)d_in[7];
  const float* bq    = (const float*)d_in[8];
  const float* Wk    = (const float*)d_in[9];
  const float* bk    = (const float*)d_in[10];
  const float* Wv    = (const float*)d_in[11];
  const float* bv    = (const float*)d_in[12];
  float* out = (float*)d_out;
  char*  ws  = (char*)d_ws;

  unsigned short* gWqT = (unsigned short*)(ws);                  // 512 KB
  float2*         c12  = (float2*)(ws + 524288);                 // 4 KB
  unsigned short* ctxP = (unsigned short*)(ws + 528384);         // 1.5 MB
  float* kbuf = (float*)(ws + 2101248);                          // 3.61 MB
  float* vbuf = (float*)(ws + 2101248 + 3784704);                // 3.61 MB

  k_prep  <<<dim3(8),       dim3(256), 0, stream>>>(Wq, ln_g, ln_b, bq, gWqT, c12);
  k_condkv<<<dim3(4,5,24),  dim3(256), 0, stream>>>(cond, idx, tln_g, tln_b, Wk, bk, Wv, bv, kbuf, vbuf);
  k_ctx   <<<dim3(8,24),    dim3(256), 0, stream>>>(kbuf, vbuf, ctxP);
  k_fused <<<dim3(2,1024),  dim3(256), 0, stream>>>(input, idx, gWqT, c12, ctxP, out);
}

// Round 6
// 416.620 us; speedup vs baseline: 1.0797x; 1.0264x over previous
//
#include <hip/hip_runtime.h>

#define LN_EPS 1e-5f

typedef __attribute__((ext_vector_type(8))) short bf16x8;
typedef __attribute__((ext_vector_type(4))) float f32x4;

__device__ __forceinline__ unsigned short f2bf(float f){
  unsigned u = __builtin_bit_cast(unsigned, f);
  u = (u + 0x7fffu + ((u >> 16) & 1u)) >> 16;
  return (unsigned short)u;
}
__device__ __forceinline__ float bf2f(unsigned short h){
  unsigned u = ((unsigned)h) << 16;
  return __builtin_bit_cast(float, u);
}

// ---------------------------------------------------------------------------
// Kernel 0: fold LN gamma into Wq (plain layout, no swizzle needed now).
//  gWqT[n][d] = bf16(g[d]*Wq[d][n])
//  c12[n] = { sum_d b[d]*Wq[d][n] + bq[n],  sum_d bf16(g*W)[d][n] }
// ---------------------------------------------------------------------------
__global__ void k_prep(const float* __restrict__ Wq, const float* __restrict__ ln_g,
                       const float* __restrict__ ln_b, const float* __restrict__ bq,
                       unsigned short* __restrict__ gWqT, float2* __restrict__ c12)
{
  __shared__ float r1[64][4], r2[64][4];
  const int tid = threadIdx.x;
  const int n0 = blockIdx.x * 64;
  const int c = tid & 63, q = tid >> 6;
  const int n = n0 + c;
  float c1p = 0.f, c2p = 0.f;
  for(int i=0;i<128;i+=4){
    ushort4 pk;
    unsigned short* pp = (unsigned short*)&pk;
    #pragma unroll
    for(int j=0;j<4;j++){
      const int d = q*128 + i + j;
      const float wv = Wq[(size_t)d*512 + n];
      const unsigned short hb = f2bf(ln_g[d] * wv);
      pp[j] = hb;
      c2p += bf2f(hb);
      c1p += ln_b[d] * wv;
    }
    *(ushort4*)(gWqT + (size_t)n*512 + q*128 + i) = pk;
  }
  r1[c][q] = c1p; r2[c][q] = c2p;
  __syncthreads();
  if(q == 0){
    float a = 0.f, b2 = 0.f;
    #pragma unroll
    for(int j=0;j<4;j++){ a += r1[c][j]; b2 += r2[c][j]; }
    c12[n] = make_float2(a + bq[n], b2);
  }
}

// ---------------------------------------------------------------------------
// Kernel 1: cond LN + K/V projection (unchanged, validated)
// ---------------------------------------------------------------------------
__global__ void k_condkv(const float* __restrict__ cond, const int* __restrict__ idx,
                         const float* __restrict__ tg, const float* __restrict__ tb,
                         const float* __restrict__ Wk, const float* __restrict__ bk,
                         const float* __restrict__ Wv, const float* __restrict__ bv,
                         float* __restrict__ kbuf, float* __restrict__ vbuf)
{
  __shared__ float cn[16][768];
  const int bc = blockIdx.z, nc = blockIdx.y, dc = blockIdx.x;
  const int b = idx[bc];
  const int n0 = nc * 16;
  int nrows = 77 - n0; if(nrows > 16) nrows = 16;
  const int w = threadIdx.x >> 6, lane = threadIdx.x & 63;

  for(int r = w; r < nrows; r += 4){
    const float* src = cond + ((size_t)b * 77 + n0 + r) * 768;
    float vals[12]; float s1 = 0.f, s2 = 0.f;
    #pragma unroll
    for(int i=0;i<12;i++){ float x = src[lane + i*64]; vals[i]=x; s1+=x; s2+=x*x; }
    #pragma unroll
    for(int off=1; off<64; off<<=1){ s1 += __shfl_xor(s1, off); s2 += __shfl_xor(s2, off); }
    const float mu  = s1 * (1.f/768.f);
    const float var = s2 * (1.f/768.f) - mu*mu;
    const float rs  = rsqrtf(var + LN_EPS);
    #pragma unroll
    for(int i=0;i<12;i++){ const int c2 = lane + i*64; cn[r][c2] = (vals[i]-mu)*rs*tg[c2] + tb[c2]; }
  }
  __syncthreads();

  const int dq = threadIdx.x & 63;
  const int part = threadIdx.x >> 6;
  const float* W    = (dc < 2) ? Wk : Wv;
  const float* bias = (dc < 2) ? bk : bv;
  float* obuf       = (dc < 2) ? kbuf : vbuf;
  const int d0 = (dc & 1) * 256 + dq * 4;

  float acc[4][4] = {};
  for(int i=0;i<768;i++){
    const float4 wv = *(const float4*)(W + (size_t)i * 512 + d0);
    #pragma unroll
    for(int j=0;j<4;j++){
      const float c = cn[part*4 + j][i];
      acc[j][0] += c * wv.x; acc[j][1] += c * wv.y;
      acc[j][2] += c * wv.z; acc[j][3] += c * wv.w;
    }
  }
  #pragma unroll
  for(int j=0;j<4;j++){
    const int r = part*4 + j, n = n0 + r;
    if(r < nrows){
      float4 o;
      o.x = acc[j][0] + bias[d0+0];
      o.y = acc[j][1] + bias[d0+1];
      o.z = acc[j][2] + bias[d0+2];
      o.w = acc[j][3] + bias[d0+3];
      *(float4*)(obuf + ((size_t)bc * 77 + n) * 512 + d0) = o;
    }
  }
}

// ---------------------------------------------------------------------------
// Kernel 2: softmax K over tokens; ctxP packed in MFMA-B-frag order
// ---------------------------------------------------------------------------
__global__ void k_ctx(const float* __restrict__ kbuf, const float* __restrict__ vbuf,
                      unsigned short* __restrict__ ctxP)
{
  __shared__ float kk[77][64];
  __shared__ float vv[77][64];
  __shared__ float inv_s[64];
  const int h = blockIdx.x, bc = blockIdx.y;
  const int tid = threadIdx.x;
  for(int e = tid; e < 77*64; e += 256){
    const int n = e >> 6, c = e & 63;
    kk[n][c] = kbuf[((size_t)bc * 77 + n) * 512 + h*64 + c];
    vv[n][c] = vbuf[((size_t)bc * 77 + n) * 512 + h*64 + c];
  }
  __syncthreads();
  if(tid < 64){
    float m = -1e30f;
    for(int n=0;n<77;n++) m = fmaxf(m, kk[n][tid]);
    float s = 0.f;
    for(int n=0;n<77;n++){ const float e = __expf(kk[n][tid] - m); kk[n][tid] = e; s += e; }
    inv_s[tid] = 1.f / s;
  }
  __syncthreads();
  #pragma unroll
  for(int j=0;j<16;j++){
    const int o = tid + 256*j;
    const int v = o >> 6, k2 = o & 63;
    float a = 0.f;
    for(int n=0;n<77;n++) a += kk[n][k2] * vv[n][v];
    const int pos = ((((k2>>5)*4 + (v>>4))*4 + ((k2>>3)&3))*16 + (v&15))*8 + (k2&7);
    ctxP[((size_t)(bc*8 + h)) * 4096 + pos] = f2bf(a * inv_s[k2]);
  }
}

// ---------------------------------------------------------------------------
// Kernel 3: THE fused kernel, v2 (lean registers).
// gemm blocks: 64t x 256n, 4 waves, wave = 64t x 64n (one head). nsplit=2,
// adjacent blockIdx pair shares the x tile via L2/L3.
//  - X: reg-staged fp32 -> bf16 micro-transpose -> 8KB dbuf LDS (swizzled)
//  - W: NO LDS; B-frags read directly from L2-resident gWqT (16B/lane)
//  - LN folded: q = rs*G - rs*mu*c2 + c1;  softmax; PV; float4 residual store
// grid (2, 1792): y<1536 gemm (bc=y>>6, tt=y&63), y>=1536 copy path.
// ---------------------------------------------------------------------------
__global__ __launch_bounds__(256, 3)
void k_fused(const float* __restrict__ input, const int* __restrict__ idx,
             const unsigned short* __restrict__ gWqT, const float2* __restrict__ c12,
             const unsigned short* __restrict__ ctxP, float* __restrict__ out)
{
  const int nt  = blockIdx.x;
  const int by  = blockIdx.y;
  const int tid = threadIdx.x;

  if(by >= 1536){
    // ---- copy path: 512 virtual blocks over the 8 non-cond batches ----
    const int cid = (by - 1536)*2 + nt;     // 0..511
    const int nb = cid >> 6, chunk = cid & 63;
    int cnt = 0, bsel = 0;
    for(int b2 = 0; b2 < 32; ++b2){
      bool member = false;
      #pragma unroll
      for(int i2 = 0; i2 < 24; ++i2) member |= (idx[i2] == b2);
      if(!member){ if(cnt == nb) bsel = b2; ++cnt; }
    }
    const float4* s = (const float4*)(input + (size_t)bsel * 2097152) + chunk*8192;
    float4*       d = (float4*)      (out   + (size_t)bsel * 2097152) + chunk*8192;
    #pragma unroll
    for(int i = 0; i < 32; ++i) d[i*256 + tid] = s[i*256 + tid];
    return;
  }

  __shared__ __align__(16) char smem[40960];
  // K-loop era: Xb0 @0 (4KB), Xb1 @4096 (4KB). rest unused.
  // epilogue era (aliased): P @0 [4][64][72]us = 36864B; mu @37376; rs @37632;
  //                         red1 @37888 [64][4]f; red2 @38912 [64][4]f.
  unsigned short* const P = (unsigned short*)smem;
  float* const mu_s = (float*)(smem + 37376);
  float* const rs_s = (float*)(smem + 37632);
  float* const red1 = (float*)(smem + 37888);
  float* const red2 = (float*)(smem + 38912);

  const int lane = tid & 63, w = tid >> 6;
  const int col = lane & 15, g = lane >> 4;
  const int bc = by >> 6, b = idx[bc];
  const int t0 = (by & 63) * 64;
  const int nbase = nt * 256;
  const float* xb = input + (size_t)b * 2097152;

  // staging: thread owns 4t x 2k per K-step. tq = t-quad (lane-contig), kb = k-pair.
  const int tq = tid & 15;           // t = tq*4 + j
  const int kb = tid >> 4;           // k rows kb*2, kb*2+1 within BK=32
  const float* xsrc = xb + (size_t)(kb*2) * 4096 + t0 + tq*4;

  // X LDS write byte offsets: row t (64B), phys slot = (k>>3) ^ ((t>>1)&3),
  // word = (kb&3). Thread writes 4x ushort2 per K-step.
  int wx[4];
  #pragma unroll
  for(int j=0;j<4;j++){
    const int t = tq*4 + j;
    wx[j] = t*64 + ((((kb>>2) ^ ((t>>1)&3)) & 3) << 4) + ((kb & 3) << 2);
  }
  // A-frag read offsets: row = mt*16+col, slot g ^ ((row>>1)&3)
  int offA[4];
  #pragma unroll
  for(int mt=0; mt<4; ++mt){
    const int row = mt*16 + col;
    offA[mt] = row*64 + ((g ^ ((row>>1)&3)) << 4);
  }
  // W row pointers (direct global B-frags, L2-resident)
  const char* wrow[4];
  #pragma unroll
  for(int ntl=0; ntl<4; ++ntl)
    wrow[ntl] = (const char*)gWqT + (size_t)(nbase + w*64 + ntl*16 + col)*1024 + g*16;

  #define PUTX(ya, yb2, Xd)                                           \
  { _Pragma("unroll")                                                 \
    for(int j=0;j<4;j++)                                              \
      *(ushort2*)((Xd) + wx[j]) = make_ushort2(f2bf((&(ya).x)[j]), f2bf((&(yb2).x)[j])); }
  #define STATS(ya, yb2)                                              \
  { _Pragma("unroll")                                                 \
    for(int j=0;j<4;j++){                                             \
      const float a_ = (&(ya).x)[j], b_ = (&(yb2).x)[j];              \
      s1[j] += a_ + b_; s2[j] += a_*a_ + b_*b_; } }

  float s1[4] = {0,0,0,0}, s2[4] = {0,0,0,0};
  f32x4 acc[4][4] = {};

  // prologue: stage k=0
  {
    float4 xa  = *(const float4*)(xsrc);
    float4 xb2 = *(const float4*)(xsrc + 4096);
    STATS(xa, xb2);
    PUTX(xa, xb2, smem);
  }
  __syncthreads();

  for(int ks = 0; ks < 16; ++ks){
    char* const Xc = smem + ((ks & 1) << 12);
    char* const Xn = smem + (((ks + 1) & 1) << 12);
    float4 xa, xb2;
    const bool pf = (ks < 15);
    if(pf){
      xa  = *(const float4*)(xsrc + (size_t)((ks+1)*32) * 4096);
      xb2 = *(const float4*)(xsrc + (size_t)((ks+1)*32 + 1) * 4096);
    }
    // B-frags straight from global (L2); A-frags from LDS
    bf16x8 bfr[4], af[4];
    #pragma unroll
    for(int ntl=0; ntl<4; ++ntl) bfr[ntl] = *(const bf16x8*)(wrow[ntl] + ks*64);
    #pragma unroll
    for(int mt=0; mt<4; ++mt) af[mt] = *(const bf16x8*)(Xc + offA[mt]);
    #pragma unroll
    for(int mt=0; mt<4; ++mt)
      #pragma unroll
      for(int ntl=0; ntl<4; ++ntl)
        acc[mt][ntl] = __builtin_amdgcn_mfma_f32_16x16x32_bf16(af[mt], bfr[ntl], acc[mt][ntl], 0, 0, 0);
    if(pf){
      STATS(xa, xb2);
      PUTX(xa, xb2, Xn);
    }
    __syncthreads();
  }
  #undef PUTX
  #undef STATS

  // ---- LN stats: reduce over kb. shfl 16,32 sums within wave; LDS across waves.
  #pragma unroll
  for(int j=0;j<4;j++){
    s1[j] += __shfl_xor(s1[j], 16); s2[j] += __shfl_xor(s2[j], 16);
    s1[j] += __shfl_xor(s1[j], 32); s2[j] += __shfl_xor(s2[j], 32);
  }
  if(lane < 16){
    #pragma unroll
    for(int j=0;j<4;j++){
      red1[(lane*4 + j)*4 + w] = s1[j];
      red2[(lane*4 + j)*4 + w] = s2[j];
    }
  }
  __syncthreads();
  if(tid < 64){
    float a = 0.f, c = 0.f;
    #pragma unroll
    for(int ww=0; ww<4; ++ww){ a += red1[tid*4 + ww]; c += red2[tid*4 + ww]; }
    const float mu  = a * (1.f/512.f);
    const float var = c * (1.f/512.f) - mu*mu;
    mu_s[tid] = mu;
    rs_s[tid] = rsqrtf(var + LN_EPS);
  }
  __syncthreads();

  // ---- LN fold + per-head feature softmax (wave owns one head) ----
  const int head = nt*4 + w;
  float c1b[4], c2v[4];
  #pragma unroll
  for(int ntl=0; ntl<4; ++ntl){
    const float2 cc = c12[nbase + w*64 + ntl*16 + col];
    c1b[ntl] = cc.x;   // includes bq
    c2v[ntl] = cc.y;
  }
  #pragma unroll
  for(int mt=0; mt<4; ++mt){
    #pragma unroll
    for(int r=0; r<4; ++r){
      const int tl = mt*16 + g*4 + r;
      const float rsr = rs_s[tl];
      const float mrc = rsr * mu_s[tl];
      float v[4];
      #pragma unroll
      for(int ntl=0; ntl<4; ++ntl)
        v[ntl] = rsr*acc[mt][ntl][r] - mrc*c2v[ntl] + c1b[ntl];
      float m = fmaxf(fmaxf(v[0],v[1]), fmaxf(v[2],v[3]));
      m = fmaxf(m, __shfl_xor(m, 1));
      m = fmaxf(m, __shfl_xor(m, 2));
      m = fmaxf(m, __shfl_xor(m, 4));
      m = fmaxf(m, __shfl_xor(m, 8));
      float s = 0.f;
      #pragma unroll
      for(int ntl=0; ntl<4; ++ntl){ v[ntl] = __expf(v[ntl] - m); s += v[ntl]; }
      s += __shfl_xor(s, 1);
      s += __shfl_xor(s, 2);
      s += __shfl_xor(s, 4);
      s += __shfl_xor(s, 8);
      const float inv = 1.f / s;
      #pragma unroll
      for(int ntl=0; ntl<4; ++ntl) acc[mt][ntl][r] = v[ntl] * inv;
    }
  }

  // ---- P -> LDS (wave-private), PV MFMA, residual + float4 store ----
  unsigned short* const Pw = P + w * (64*72);
  #pragma unroll
  for(int mt=0; mt<4; ++mt)
    #pragma unroll
    for(int ntl=0; ntl<4; ++ntl)
      #pragma unroll
      for(int r=0; r<4; ++r)
        Pw[(mt*16 + g*4 + r)*72 + ntl*16 + col] = f2bf(acc[mt][ntl][r]);

  const unsigned short* cp = ctxP + (size_t)(bc*8 + head) * 4096;
  f32x4 y[4][4] = {};
  #pragma unroll
  for(int ks2=0; ks2<2; ++ks2){
    bf16x8 pa[4];
    #pragma unroll
    for(int mt=0; mt<4; ++mt)
      pa[mt] = *(const bf16x8*)(Pw + (mt*16 + col)*72 + ks2*32 + g*8);
    bf16x8 cv[4];
    #pragma unroll
    for(int vt=0; vt<4; ++vt)
      cv[vt] = *(const bf16x8*)(cp + (size_t)(((ks2*4 + vt)*4 + g)*16 + col) * 8);
    #pragma unroll
    for(int mt=0; mt<4; ++mt)
      #pragma unroll
      for(int vt=0; vt<4; ++vt)
        y[mt][vt] = __builtin_amdgcn_mfma_f32_16x16x32_bf16(pa[mt], cv[vt], y[mt][vt], 0, 0, 0);
  }

  float* const ob = out + (size_t)b * 2097152;
  #pragma unroll
  for(int mt=0; mt<4; ++mt)
    #pragma unroll
    for(int vt=0; vt<4; ++vt){
      const size_t a = (size_t)(head*64 + vt*16 + col)*4096
                     + (size_t)(t0 + mt*16 + g*4);
      const float4 xr4 = *(const float4*)(xb + a);
      float4 o4;
      o4.x = xr4.x + y[mt][vt][0];
      o4.y = xr4.y + y[mt][vt][1];
      o4.z = xr4.z + y[mt][vt][2];
      o4.w = xr4.w + y[mt][vt][3];
      *(float4*)(ob + a) = o4;
    }
}

// ---------------------------------------------------------------------------
extern "C" void kernel_launch(void* const* d_in, const int* in_sizes, int n_in,
                              void* d_out, int out_size, void* d_ws, size_t ws_size,
                              hipStream_t stream)
{
  const float* input = (const float*)d_in[0];
  const float* cond  = (const float*)d_in[1];
  const int*   idx   = (const int*)d_in[2];
  const float* ln_g  = (const float*)d_in[3];
  const float* ln_b  = (const float*)d_in[4];
  const float* tln_g = (const float*)d_in[5];
  const float* tln_b = (const float*)d_in[6];
  const float* Wq    = (const float*)d_in[7];
  const float* bq    = (const float*)d_in[8];
  const float* Wk    = (const float*)d_in[9];
  const float* bk    = (const float*)d_in[10];
  const float* Wv    = (const float*)d_in[11];
  const float* bv    = (const float*)d_in[12];
  float* out = (float*)d_out;
  char*  ws  = (char*)d_ws;

  unsigned short* gWqT = (unsigned short*)(ws);                  // 512 KB
  float2*         c12  = (float2*)(ws + 524288);                 // 4 KB
  unsigned short* ctxP = (unsigned short*)(ws + 528384);         // 1.5 MB
  float* kbuf = (float*)(ws + 2101248);                          // 3.61 MB
  float* vbuf = (float*)(ws + 2101248 + 3784704);                // 3.61 MB

  k_prep  <<<dim3(8),       dim3(256), 0, stream>>>(Wq, ln_g, ln_b, bq, gWqT, c12);
  k_condkv<<<dim3(4,5,24),  dim3(256), 0, stream>>>(cond, idx, tln_g, tln_b, Wk, bk, Wv, bv, kbuf, vbuf);
  k_ctx   <<<dim3(8,24),    dim3(256), 0, stream>>>(kbuf, vbuf, ctxP);
  k_fused <<<dim3(2,1792),  dim3(256), 0, stream>>>(input, idx, gWqT, c12, ctxP, out);
}